// Round 7
// baseline (1627.760 us; speedup 1.0000x reference)
//
#include <hip/hip_runtime.h>
#include <math.h>

typedef _Float16 f16;
typedef f16  f16x2 __attribute__((ext_vector_type(2)));
typedef f16  f16x4 __attribute__((ext_vector_type(4)));
typedef f16  f16x8 __attribute__((ext_vector_type(8)));
typedef float f32x4 __attribute__((ext_vector_type(4)));

#define F4(p)  (*(float4*)(p))
#define CF4(p) (*(const float4*)(p))

namespace {
constexpr int LL = 4096;   // sequence
constexpr int HH = 64;     // channels
constexpr int GRID = 512;  // persistent blocks; capacity: 44KB LDS -> 3/CU,
                           // __launch_bounds__(256,2) -> >=2/CU => >=512 resident

__device__ __forceinline__ float gelu_fast(float x) {
    float inner = 0.7978845608028654f * (x + 0.044715f * x * x * x);
    float e = __expf(-2.0f * inner);
    return x / (1.0f + e);
}

__device__ __forceinline__ f32x4 mfma16(f16x8 a, f16x8 b, f32x4 c) {
    return __builtin_amdgcn_mfma_f32_16x16x32_f16(a, b, c, 0, 0, 0);
}

// software grid barrier (cooperative-groups pattern); one counter per barrier id
__device__ __forceinline__ void grid_bar(int* cnt, int id) {
    __syncthreads();
    __threadfence();                       // release: flush our writes
    if (threadIdx.x == 0) {
        atomicAdd(&cnt[id], 1);            // device-scope RMW
        while (__hip_atomic_load(&cnt[id], __ATOMIC_RELAXED,
                                 __HIP_MEMORY_SCOPE_AGENT) < GRID)
            __builtin_amdgcn_s_sleep(4);   // ~256-cyc backoff
    }
    __syncthreads();
    __threadfence();                       // acquire: invalidate stale L1
}
} // namespace

// ---------------------------------------------------------------------------
// Persistent mega-kernel. Phase bodies are the round-5 kernels (214 us),
// work-units remapped onto 512 blocks; phases separated by grid_bar.
// LDS pool (44032 B) = max(recon 43k, spec 32k, dft 23k, lift 21k).
// ---------------------------------------------------------------------------
__global__ __launch_bounds__(256, 2) void k_mega(
        const float* __restrict__ u,   const float* __restrict__ z,
        const float* __restrict__ wl,  const float* __restrict__ bl,
        const float* __restrict__ wsk, const float* __restrict__ bsk,
        const float* __restrict__ wr,  const float* __restrict__ wi,
        const float* __restrict__ wp1, const float* __restrict__ bp1,
        const float* __restrict__ wp2, const float* __restrict__ bp2,
        f16* __restrict__ ws, int* __restrict__ cnt,
        float* __restrict__ out) {
    __shared__ __attribute__((aligned(16))) unsigned char pool[44032];
    __shared__ float bsh[64];
    const int bid = blockIdx.x;
    const int t = threadIdx.x;

    // workspace layout (f16 units)
    f16* XTa  = ws;                   // [b][l][h]
    f16* XTb  = XTa + 8388608;
    f16* Tdt  = XTb + 8388608;        // [m2][l]
    f16* Ttr  = Tdt + 524288;         // [l][m2]
    f16* Ofh  = Ttr + 524288;         // [b][o][m2]
    f16* wskh = Ofh + 262144;
    f16* wrh  = wskh + 16384;
    f16* wih  = wrh + 1048576;

    // ===================== phase 0: lift (1 unit) + twiddle/convert (4 units)
    {   // ---- lift: XT0[b][l][h], 8h x 8l register tile per thread
        constexpr int IP = 260;
        float* in_s = (float*)pool;           // 16 x 260
        float* wsh  = (float*)pool + 4160;    // 64 x 16
        const int lt = bid & 15, b = bid >> 4;
        const int l0 = lt * 256;
        for (int i = t; i < 1024; i += 256) wsh[i] = wl[i];
        if (t < 64) bsh[t] = bl[t];
#pragma unroll
        for (int q = 0; q < 2; ++q) {
            int f = t + q * 256;
            int l = f >> 1, cq = (f & 1) * 4;
            float4 v = CF4(u + ((size_t)b * LL + l0 + l) * 8 + cq);
            in_s[(cq + 0) * IP + l] = v.x;
            in_s[(cq + 1) * IP + l] = v.y;
            in_s[(cq + 2) * IP + l] = v.z;
            in_s[(cq + 3) * IP + l] = v.w;
        }
        for (int f = t; f < 8 * 256; f += 256) {
            int c = f >> 8, l = f & 255;
            in_s[(8 + c) * IP + l] = z[b * 8 + c];
        }
        __syncthreads();
        const int hg = t >> 5, lsub = t & 31;
        float acc[8][8] = {};
        for (int c = 0; c < 16; ++c) {
            float wv[8], inv[8];
#pragma unroll
            for (int i = 0; i < 8; ++i) wv[i] = wsh[(hg * 8 + i) * 16 + c];
#pragma unroll
            for (int j = 0; j < 8; ++j) inv[j] = in_s[c * IP + lsub + 32 * j];
#pragma unroll
            for (int i = 0; i < 8; ++i)
#pragma unroll
                for (int j = 0; j < 8; ++j) acc[i][j] += wv[i] * inv[j];
        }
#pragma unroll
        for (int j = 0; j < 8; ++j) {
            __attribute__((aligned(16))) f16 hv[8];
#pragma unroll
            for (int i = 0; i < 8; ++i) hv[i] = (f16)(acc[i][j] + bsh[hg * 8 + i]);
            int l = l0 + lsub + 32 * j;
            F4(XTa + ((size_t)b * LL + l) * HH + hg * 8) = CF4(hv);
        }
    }
    for (int uu = bid; uu < 2048; uu += GRID) {   // ---- twiddles + converts
        if (uu < 1024) {
            const int tb = uu;
            const float w0 = 6.283185307179586f / 4096.0f;
            {   // Tdt: lane runs along l
                int m = tb >> 4;
                int l = ((tb & 15) << 8) + t;
                float s, c;
                sincosf((float)((l * m) & 4095) * w0, &s, &c);
                Tdt[(size_t)(2 * m) * LL + l]     = (f16)c;
                Tdt[(size_t)(2 * m + 1) * LL + l] = (f16)(-s);
            }
            {   // Ttr: lane runs along m2
                int l = tb * 4 + (t >> 6);
                int m = t & 63;
                float s, c;
                sincosf((float)((l * m) & 4095) * w0, &s, &c);
                const float sc = 1.0f / 4096.0f;
                f16x2 pv;
                pv.x = (f16)((m == 0) ? sc : 2.0f * sc * c);
                pv.y = (f16)((m == 0) ? 0.0f : -2.0f * sc * s);
                *(f16x2*)(Ttr + (size_t)l * 128 + 2 * m) = pv;
            }
            if (tb < 64) {
                int idx = tb * 256 + t;
                wskh[idx] = (f16)wsk[idx];
            }
        } else {
            const int cb = uu - 1024;
            size_t base = (size_t)cb * 1024 + t * 4;
            float4 vr = CF4(wr + base);
            float4 vi = CF4(wi + base);
            f16x4 hr, hi;
            hr.x = (f16)vr.x; hr.y = (f16)vr.y; hr.z = (f16)vr.z; hr.w = (f16)vr.w;
            hi.x = (f16)vi.x; hi.y = (f16)vi.y; hi.z = (f16)vi.z; hi.w = (f16)vi.w;
            *(f16x4*)(wrh + base) = hr;
            *(f16x4*)(wih + base) = hi;
        }
    }
    grid_bar(cnt, 0);

    // ===================== layer loop
    f16* xtc = XTa; f16* xtn = XTb;
    int barid = 1;
    for (int layer = 0; layer < 4; ++layer) {
        f16* Yb = xtn;   // split-K DFT partials overlay the dead XT buffer

        // ---- dft: 512 units (16 = ch*2+hhalf, 32 b), tile 32h x 128m2, K=512
        {
            f16* Asl = (f16*)pool;           // 32 x 72
            f16* Bsl = (f16*)pool + 2304;    // 128 x 72
            const int ch = (bid & 15) >> 1, h0 = (bid & 1) * 32, b = bid >> 4;
            const int lane = t & 63, wid = t >> 6;
            const int mh = (wid & 1) * 16, n0 = (wid >> 1) * 64;
            const int fm = lane & 15, fq = lane >> 4;
            f32x4 acc[4] = {};
            for (int k0 = 0; k0 < 512; k0 += 64) {
                const int l0 = ch * 512 + k0;
                __syncthreads();
                {   // A: XT[b][l][h0..h0+32] -> Asl[h][l] (2-way LDS alias: free)
                    int seg = t >> 6;
                    f16x8 v = *(const f16x8*)(xtc + ((size_t)b * LL + l0 + lane) * HH + h0 + seg * 8);
#pragma unroll
                    for (int i = 0; i < 8; ++i) Asl[(seg * 8 + i) * 72 + lane] = v[i];
                }
#pragma unroll
                for (int p = 0; p < 4; ++p) {   // B: Tdt[m2][l chunk]
                    int r = (t >> 3) + p * 32;
                    F4(&Bsl[r * 72 + (t & 7) * 8]) = CF4(Tdt + (size_t)r * LL + l0 + (t & 7) * 8);
                }
                __syncthreads();
#pragma unroll
                for (int ks = 0; ks < 64; ks += 32) {
                    f16x8 a = *(const f16x8*)&Asl[(mh + fm) * 72 + ks + fq * 8];
#pragma unroll
                    for (int j = 0; j < 4; ++j) {
                        f16x8 bj = *(const f16x8*)&Bsl[(n0 + j * 16 + fm) * 72 + ks + fq * 8];
                        acc[j] = mfma16(a, bj, acc[j]);
                    }
                }
            }
            f16* yp = Yb + ((size_t)ch * 2048 + b * HH + h0) * 128;
#pragma unroll
            for (int j = 0; j < 4; ++j)
#pragma unroll
                for (int r = 0; r < 4; ++r)
                    yp[(size_t)(mh + fq * 4 + r) * 128 + n0 + j * 16 + fm] = (f16)acc[j][r];
        }
        grid_bar(cnt, barid++);

        // ---- spec: 64 units (b, o-half); stage Xf[b] ONCE per block
        if (bid < 64) {
            float* xsh = (float*)pool;   // 64 x 128 fp32
            const int b = bid >> 1, oh = bid & 1;
#pragma unroll
            for (int i = 0; i < 4; ++i) {
                int g = t + i * 256;
                float s[8] = {};
#pragma unroll
                for (int c = 0; c < 8; ++c) {   // ascending ch (deterministic)
                    f16x8 v = *(const f16x8*)(Yb + ((size_t)c * 2048 + b * HH) * 128 + g * 8);
#pragma unroll
                    for (int e = 0; e < 8; ++e) s[e] += (float)v[e];
                }
#pragma unroll
                for (int e = 0; e < 8; ++e) xsh[g * 8 + e] = s[e];
            }
            __syncthreads();
            const int m = t & 63, og = t >> 6;
            float are[8] = {}, aim[8] = {};
            const float2* xs2 = (const float2*)xsh;
            for (int i = 0; i < 64; ++i) {
                float2 xv = xs2[i * 64 + m];
#pragma unroll
                for (int k = 0; k < 8; ++k) {
                    int o = oh * 32 + og + 4 * k;
                    size_t widx = (((size_t)layer * HH + o) * HH + i) * 64 + m;
                    float wrv = (float)wrh[widx];
                    float wiv = (float)wih[widx];
                    are[k] += xv.x * wrv - xv.y * wiv;
                    aim[k] += xv.x * wiv + xv.y * wrv;
                }
            }
#pragma unroll
            for (int k = 0; k < 8; ++k) {
                int o = oh * 32 + og + 4 * k;
                f16x2 ov; ov.x = (f16)are[k]; ov.y = (f16)aim[k];
                *(f16x2*)(Ofh + ((size_t)b * HH + o) * 128 + 2 * m) = ov;
            }
        }
        grid_bar(cnt, barid++);

        if (layer < 3) {
            // ---- recon: 1024 units (32 lt, 32 b), 2 per block
            f16* Amain = (f16*)pool;            // 64 x 200
            f16* Bmain = (f16*)pool + 12800;    // 128 x 72 (+ transpose reuse)
            for (int uu = bid; uu < 1024; uu += GRID) {
                const int lt = uu & 31, l0 = lt * 128, b = uu >> 5;
                const int lane = t & 63, wid = t >> 6;
                const int m0 = (wid & 1) * 32, n0 = (wid >> 1) * 64;
                const int fm = lane & 15, fq = lane >> 4;
                f32x4 acc[2][4] = {};
                {   // stage A = [Of[b] | wskh[layer]]
                    int seg = t & 15, row = t >> 4;
#pragma unroll
                    for (int p = 0; p < 4; ++p) {
                        int r = row + p * 16;
                        F4(&Amain[r * 200 + seg * 8]) = CF4(Ofh + ((size_t)(b * HH + r)) * 128 + seg * 8);
                    }
                    int seg8 = t & 7, row8 = t >> 3;
#pragma unroll
                    for (int p = 0; p < 2; ++p) {
                        int r = row8 + p * 32;
                        F4(&Amain[r * 200 + 128 + seg8 * 8]) =
                            CF4(wskh + ((size_t)(layer * HH + r)) * HH + seg8 * 8);
                    }
                }
                const int srow = t >> 3, sseg = t & 7;
                for (int k0 = 0; k0 < 192; k0 += 64) {
                    __syncthreads();
#pragma unroll
                    for (int p = 0; p < 4; ++p) {
                        int r = srow + p * 32;
                        const f16* src = (k0 < 128)
                            ? (Ttr + (size_t)(l0 + r) * 128 + k0 + sseg * 8)
                            : (xtc + ((size_t)b * LL + l0 + r) * HH + sseg * 8);
                        F4(&Bmain[r * 72 + sseg * 8]) = CF4(src);
                    }
                    __syncthreads();
#pragma unroll
                    for (int ks = 0; ks < 64; ks += 32) {
                        f16x8 a0 = *(const f16x8*)&Amain[(m0 + fm) * 200 + k0 + ks + fq * 8];
                        f16x8 a1 = *(const f16x8*)&Amain[(m0 + 16 + fm) * 200 + k0 + ks + fq * 8];
#pragma unroll
                        for (int j = 0; j < 4; ++j) {
                            f16x8 bj = *(const f16x8*)&Bmain[(n0 + j * 16 + fm) * 72 + ks + fq * 8];
                            acc[0][j] = mfma16(a0, bj, acc[0][j]);
                            acc[1][j] = mfma16(a1, bj, acc[1][j]);
                        }
                    }
                }
                __syncthreads();   // frag reads done; reuse Bmain as [l][o]
#pragma unroll
                for (int i = 0; i < 2; ++i)
#pragma unroll
                    for (int r = 0; r < 4; ++r) {
                        int row = m0 + i * 16 + fq * 4 + r;
                        float bias = bsk[layer * HH + row];
#pragma unroll
                        for (int j = 0; j < 4; ++j) {
                            float v = gelu_fast(acc[i][j][r] + bias);
                            int lc = n0 + j * 16 + fm;
                            Bmain[lc * 72 + row] = (f16)v;
                        }
                    }
                __syncthreads();
                {   // write XTn[b][l][o]
                    int row = t >> 1, half = t & 1;
                    f16* dst = xtn + ((size_t)b * LL + l0 + row) * HH + half * 32;
                    const f16* src = &Bmain[row * 72 + half * 32];
#pragma unroll
                    for (int i = 0; i < 4; ++i)
                        F4(dst + i * 8) = CF4(src + i * 8);
                }
            }
            grid_bar(cnt, barid++);
            f16* tmp = xtc; xtc = xtn; xtn = tmp;
        } else {
            // ---- final: 32 units (b); per-thread row reads (weights L2-hot)
            if (bid < 32) {
                float* tl = (float*)pool;          // 128
                float* xl = tl + 128;              // 64
                float* x4 = xl + 64;               // 64
                float* y  = x4 + 64;               // 128
                const int b = bid;
                if (t < 128) tl[t] = (float)Ttr[(size_t)(LL - 1) * 128 + t];
                if (t < 64)  xl[t] = (float)xtc[((size_t)b * LL + (LL - 1)) * HH + t];
                __syncthreads();
                if (t < 64) {
                    const int o = t;
                    float acc = bsk[3 * HH + o];
                    const f16* ofp = Ofh + ((size_t)(b * HH + o)) * 128;
                    for (int k = 0; k < 128; ++k) acc += (float)ofp[k] * tl[k];
                    const float* wp = wsk + (size_t)(3 * HH + o) * HH;
                    for (int i = 0; i < 64; ++i) acc += wp[i] * xl[i];
                    x4[o] = acc;   // no gelu after last FNO layer
                }
                __syncthreads();
                if (t < 128) {
                    float acc = bp1[t];
                    for (int h = 0; h < 64; ++h) acc += wp1[t * 64 + h] * x4[h];
                    y[t] = gelu_fast(acc);
                }
                __syncthreads();
                if (t < 8) {
                    float acc = bp2[t];
                    for (int p = 0; p < 128; ++p) acc += wp2[t * 128 + p] * y[p];
                    out[b * 8 + t] = acc;   // float32 output
                }
            }
        }
    }
}

// ---------------------------------------------------------------------------
extern "C" void kernel_launch(void* const* d_in, const int* in_sizes, int n_in,
                              void* d_out, int out_size, void* d_ws, size_t ws_size,
                              hipStream_t stream) {
    (void)in_sizes; (void)n_in; (void)out_size; (void)ws_size;
    const float* u   = (const float*)d_in[0];
    const float* z   = (const float*)d_in[1];
    // d_in[2] = t, unused by the reference
    const float* wl  = (const float*)d_in[3];
    const float* bl  = (const float*)d_in[4];
    const float* swr = (const float*)d_in[5];
    const float* swi = (const float*)d_in[6];
    const float* wsk = (const float*)d_in[7];
    const float* bsk = (const float*)d_in[8];
    const float* wp1 = (const float*)d_in[9];
    const float* bp1 = (const float*)d_in[10];
    const float* wp2 = (const float*)d_in[11];
    const float* bp2 = (const float*)d_in[12];
    float* out = (float*)d_out;

    f16* ws = (f16*)d_ws;
    // data region ends at 20,201,472 f16 (~40.4 MB); barrier counters after it
    int* cnt = (int*)(ws + 20201472);

    hipMemsetAsync(cnt, 0, 64, stream);   // zero 16 barrier counters
    k_mega<<<GRID, 256, 0, stream>>>(u, z, wl, bl, wsk, bsk, swr, swi,
                                     wp1, bp1, wp2, bp2, ws, cnt, out);
}

// Round 8
// 317.048 us; speedup vs baseline: 5.1341x; 5.1341x over previous
//
#include <hip/hip_runtime.h>
#include <math.h>

typedef _Float16 f16;
typedef f16  f16x2 __attribute__((ext_vector_type(2)));
typedef f16  f16x4 __attribute__((ext_vector_type(4)));
typedef f16  f16x8 __attribute__((ext_vector_type(8)));
typedef float f32x4 __attribute__((ext_vector_type(4)));

#define F4(p)  (*(float4*)(p))
#define CF4(p) (*(const float4*)(p))

namespace {
constexpr int LL = 4096;   // sequence
constexpr int HH = 64;     // channels

__device__ __forceinline__ float gelu_fast(float x) {
    // 0.5x(1+tanh(i)) == x*sigmoid(2i); exp-neg form is NaN-free at +/-inf
    float inner = 0.7978845608028654f * (x + 0.044715f * x * x * x);
    float e = __expf(-2.0f * inner);
    return x / (1.0f + e);
}

__device__ __forceinline__ f32x4 mfma16(f16x8 a, f16x8 b, f32x4 c) {
    return __builtin_amdgcn_mfma_f32_16x16x32_f16(a, b, c, 0, 0, 0);
}
} // namespace

// ---------------------------------------------------------------------------
// k_init: fused lift [0,512) + twiddle [512,1536) + wr/wi fp16 cvt [1536,2560)
//   Tdt[m2][l]:  cos(2pi m l/L), -sin               (DFT weights, f16)
//   Ttr[l][m2]: (m==0?1:2cos)/L, (m==0?0:-2sin)/L   (irfft weights, f16)
// ---------------------------------------------------------------------------
__global__ __launch_bounds__(256) void k_init(const float* __restrict__ u,
                                              const float* __restrict__ z,
                                              const float* __restrict__ wl,
                                              const float* __restrict__ bl,
                                              const float* __restrict__ wsk,
                                              const float* __restrict__ wr,
                                              const float* __restrict__ wi,
                                              f16* __restrict__ Tdt,
                                              f16* __restrict__ Ttr,
                                              f16* __restrict__ wskh,
                                              f16* __restrict__ wrh,
                                              f16* __restrict__ wih,
                                              f16* __restrict__ XT0) {
    const int bid = blockIdx.x;
    const int t = threadIdx.x;
    if (bid < 512) {
        // ---- lift: XT0[b][l][h], register-tiled 8h x 8l per thread
        const int b = bid >> 4;
        const int l0 = (bid & 15) * 256;
        constexpr int IP = 260;
        __shared__ float in_s[16 * IP];
        __shared__ float wsh[64 * 16];
        __shared__ float bsh[64];
        for (int i = t; i < 1024; i += 256) wsh[i] = wl[i];
        if (t < 64) bsh[t] = bl[t];
#pragma unroll
        for (int q = 0; q < 2; ++q) {
            int f = t + q * 256;
            int l = f >> 1, cq = (f & 1) * 4;
            float4 v = CF4(u + ((size_t)b * LL + l0 + l) * 8 + cq);
            in_s[(cq + 0) * IP + l] = v.x;
            in_s[(cq + 1) * IP + l] = v.y;
            in_s[(cq + 2) * IP + l] = v.z;
            in_s[(cq + 3) * IP + l] = v.w;
        }
        for (int f = t; f < 8 * 256; f += 256) {
            int c = f >> 8, l = f & 255;
            in_s[(8 + c) * IP + l] = z[b * 8 + c];
        }
        __syncthreads();
        const int hg = t >> 5, lsub = t & 31;
        float acc[8][8] = {};
        for (int c = 0; c < 16; ++c) {
            float wv[8], inv[8];
#pragma unroll
            for (int i = 0; i < 8; ++i) wv[i] = wsh[(hg * 8 + i) * 16 + c];
#pragma unroll
            for (int j = 0; j < 8; ++j) inv[j] = in_s[c * IP + lsub + 32 * j];
#pragma unroll
            for (int i = 0; i < 8; ++i)
#pragma unroll
                for (int j = 0; j < 8; ++j) acc[i][j] += wv[i] * inv[j];
        }
#pragma unroll
        for (int j = 0; j < 8; ++j) {
            __attribute__((aligned(16))) f16 hv[8];
#pragma unroll
            for (int i = 0; i < 8; ++i) hv[i] = (f16)(acc[i][j] + bsh[hg * 8 + i]);
            int l = l0 + lsub + 32 * j;
            F4(XT0 + ((size_t)b * LL + l) * HH + hg * 8) = CF4(hv);
        }
    } else if (bid < 1536) {
        // ---- twiddle (both orientations coalesced)
        const int tb = bid - 512;
        const float w0 = 6.283185307179586f / 4096.0f;
        {   // Tdt: lane runs along l
            int m = tb >> 4;
            int l = ((tb & 15) << 8) + t;
            float s, c;
            sincosf((float)((l * m) & 4095) * w0, &s, &c);
            Tdt[(size_t)(2 * m) * LL + l]     = (f16)c;
            Tdt[(size_t)(2 * m + 1) * LL + l] = (f16)(-s);
        }
        {   // Ttr: lane runs along m2 (4B per lane)
            int l = tb * 4 + (t >> 6);
            int m = t & 63;
            float s, c;
            sincosf((float)((l * m) & 4095) * w0, &s, &c);
            const float sc = 1.0f / 4096.0f;
            f16x2 pv;
            pv.x = (f16)((m == 0) ? sc : 2.0f * sc * c);
            pv.y = (f16)((m == 0) ? 0.0f : -2.0f * sc * s);
            *(f16x2*)(Ttr + (size_t)l * 128 + 2 * m) = pv;
        }
        if (tb < 64) {
            int idx = tb * 256 + t;
            wskh[idx] = (f16)wsk[idx];
        }
    } else {
        // ---- wr/wi -> f16 (4 elements each per thread)
        const int cb = bid - 1536;
        size_t base = (size_t)cb * 1024 + t * 4;
        float4 vr = CF4(wr + base);
        float4 vi = CF4(wi + base);
        f16x4 hr, hi;
        hr.x = (f16)vr.x; hr.y = (f16)vr.y; hr.z = (f16)vr.z; hr.w = (f16)vr.w;
        hi.x = (f16)vi.x; hi.y = (f16)vi.y; hi.z = (f16)vi.z; hi.w = (f16)vi.w;
        *(f16x4*)(wrh + base) = hr;
        *(f16x4*)(wih + base) = hi;
    }
}

// ---------------------------------------------------------------------------
// Fused DFT + spectral mix. grid 64: bid = mhalf*32 + b  (both m-halves of a
// batch land on XCD b%8 -> XT[b] HBM once, L2 twice). block 1024 (16 waves).
// Phase 1: Xf[64h][64 m2] = sum_{l=0..4095} XT[b][l][h] * Tdt[mh*64+m2][l]
//   full-K MFMA, acc in registers (no split-K partials, no f16 round-trip).
//   Single-buffer LDS staging with register prefetch of the next 128-l chunk.
// Phase 2: Of[b][o][m2] = sum_i Xf[i][m2] * (wr+j*wi)[o][i][m]  (fp32 math).
// ---------------------------------------------------------------------------
__global__ __launch_bounds__(1024) void k_dftspec(const f16* __restrict__ XT,
                                                  const f16* __restrict__ Tdt,
                                                  const f16* __restrict__ wrh,
                                                  const f16* __restrict__ wih,
                                                  f16* __restrict__ Ofh, int layer) {
    __shared__ __attribute__((aligned(16))) f16 pool[17408];   // 34816 B
    f16* Asl = pool;            // 64 h  x 136 (l-chunk)
    f16* Bsl = pool + 8704;     // 64 m2 x 136 (l-chunk)
    float* xsh = (float*)pool;  // overlay after K-loop: 64 h x 66 fp32
    const int bid = blockIdx.x;
    const int b = bid & 31, mhalf = bid >> 5;
    const int t = threadIdx.x;
    const int wid = t >> 6, lane = t & 63;
    const int wm = wid & 3, wn = wid >> 2;     // wave tile: h band 16, m2 band 16
    const int fm = lane & 15, fq = lane >> 4;
    // staging maps: A: lane runs along l (2-way LDS alias on transpose = free)
    const int sa_seg = t >> 7, sa_l = t & 127;  // 8 h-segs x 128 l
    const int sb_row = t >> 4, sb_seg = t & 15; // 64 m2 rows x 16 8-f16 segs

    f16x8 ra = *(const f16x8*)(XT + ((size_t)b * LL + sa_l) * HH + sa_seg * 8);
    f16x8 rb = *(const f16x8*)(Tdt + (size_t)(mhalf * 64 + sb_row) * LL + sb_seg * 8);
    f32x4 acc = {};
    for (int c = 0; c < 32; ++c) {
        __syncthreads();
#pragma unroll
        for (int i = 0; i < 8; ++i) Asl[(sa_seg * 8 + i) * 136 + sa_l] = ra[i];
        *(f16x8*)&Bsl[sb_row * 136 + sb_seg * 8] = rb;
        __syncthreads();
        if (c < 31) {   // prefetch next chunk while computing this one
            int l0 = (c + 1) * 128;
            ra = *(const f16x8*)(XT + ((size_t)b * LL + l0 + sa_l) * HH + sa_seg * 8);
            rb = *(const f16x8*)(Tdt + (size_t)(mhalf * 64 + sb_row) * LL + l0 + sb_seg * 8);
        }
#pragma unroll
        for (int ks = 0; ks < 128; ks += 32) {
            f16x8 a  = *(const f16x8*)&Asl[(wm * 16 + fm) * 136 + ks + fq * 8];
            f16x8 bv = *(const f16x8*)&Bsl[(wn * 16 + fm) * 136 + ks + fq * 8];
            acc = mfma16(a, bv, acc);
        }
    }
    __syncthreads();   // all MFMA LDS reads done -> overlay xsh
#pragma unroll
    for (int r = 0; r < 4; ++r)   // C layout: col=lane&15, row=quad*4+reg
        xsh[(wm * 16 + fq * 4 + r) * 66 + wn * 16 + fm] = acc[r];
    __syncthreads();
    // ---- phase 2: spectral mix (each thread: 2 o's x 1 m)
    const int mloc = t & 31, og = t >> 5;   // og 0..31
    const int mg = mhalf * 32 + mloc;
    const f16* wr0 = wrh + ((size_t)(layer * HH + og) * HH) * 64 + mg;
    const f16* wi0 = wih + ((size_t)(layer * HH + og) * HH) * 64 + mg;
    const f16* wr1 = wr0 + (size_t)32 * HH * 64;
    const f16* wi1 = wi0 + (size_t)32 * HH * 64;
    float are0 = 0, aim0 = 0, are1 = 0, aim1 = 0;
#pragma unroll 8
    for (int i = 0; i < 64; ++i) {
        float2 xv = *(const float2*)&xsh[i * 66 + 2 * mloc];
        float w0r = (float)wr0[(size_t)i * 64], w0i = (float)wi0[(size_t)i * 64];
        float w1r = (float)wr1[(size_t)i * 64], w1i = (float)wi1[(size_t)i * 64];
        are0 += xv.x * w0r - xv.y * w0i;  aim0 += xv.x * w0i + xv.y * w0r;
        are1 += xv.x * w1r - xv.y * w1i;  aim1 += xv.x * w1i + xv.y * w1r;
    }
    f16x2 o0; o0.x = (f16)are0; o0.y = (f16)aim0;
    f16x2 o1; o1.x = (f16)are1; o1.y = (f16)aim1;
    *(f16x2*)(Ofh + ((size_t)b * HH + og) * 128 + 2 * mg)      = o0;
    *(f16x2*)(Ofh + ((size_t)b * HH + og + 32) * 128 + 2 * mg) = o1;
}

// ---------------------------------------------------------------------------
// Recon (layers 0..2), fp16 MFMA, fused K=192 = [Of | Wsk] x [Ttr ; X^T]:
//   x_next[b][o][l] = gelu( sum_k A[o][k]*B[k][l] + bsk[o] )
// Output in transposed layout XTn[b][l][o] (via LDS transpose).
// grid (32 l-tiles of 128, 32 b), block 256 (4 waves), tile 64 o x 128 l.
// ---------------------------------------------------------------------------
__global__ __launch_bounds__(256) void k_recon(const f16* __restrict__ Ofh,
                                               const f16* __restrict__ XT,
                                               const f16* __restrict__ Ttr,
                                               const f16* __restrict__ wskh,
                                               const float* __restrict__ bsk,
                                               f16* __restrict__ XTn,
                                               int layer) {
    __shared__ f16 Asl[64 * 200];   // [o][k 0..191], pitch 200
    __shared__ f16 Bsl[128 * 72];   // [l][k-chunk], pitch 72; reused for transpose
    const int t = threadIdx.x;
    const int l0 = blockIdx.x * 128, b = blockIdx.y;
    const int lane = t & 63, wid = t >> 6;
    const int m0 = (wid & 1) * 32, n0 = (wid >> 1) * 64;
    const int fm = lane & 15, fq = lane >> 4;
    f32x4 acc[2][4] = {};
    {   // stage A = [Of[b] | wskh[layer]]
        int seg = t & 15, row = t >> 4;
#pragma unroll
        for (int p = 0; p < 4; ++p) {
            int r = row + p * 16;
            F4(&Asl[r * 200 + seg * 8]) = CF4(Ofh + ((size_t)(b * HH + r)) * 128 + seg * 8);
        }
        int seg8 = t & 7, row8 = t >> 3;
#pragma unroll
        for (int p = 0; p < 2; ++p) {
            int r = row8 + p * 32;
            F4(&Asl[r * 200 + 128 + seg8 * 8]) =
                CF4(wskh + ((size_t)(layer * HH + r)) * HH + seg8 * 8);
        }
    }
    const int srow = t >> 3, sseg = t & 7;
    for (int k0 = 0; k0 < 192; k0 += 64) {
        __syncthreads();
#pragma unroll
        for (int p = 0; p < 4; ++p) {   // B rows l: Ttr[l][k0..] or XT[b][l][h]
            int r = srow + p * 32;
            const f16* src = (k0 < 128)
                ? (Ttr + (size_t)(l0 + r) * 128 + k0 + sseg * 8)
                : (XT + ((size_t)b * LL + l0 + r) * HH + sseg * 8);
            F4(&Bsl[r * 72 + sseg * 8]) = CF4(src);
        }
        __syncthreads();
#pragma unroll
        for (int ks = 0; ks < 64; ks += 32) {
            f16x8 a0 = *(const f16x8*)&Asl[(m0 + fm) * 200 + k0 + ks + fq * 8];
            f16x8 a1 = *(const f16x8*)&Asl[(m0 + 16 + fm) * 200 + k0 + ks + fq * 8];
#pragma unroll
            for (int j = 0; j < 4; ++j) {
                f16x8 bj = *(const f16x8*)&Bsl[(n0 + j * 16 + fm) * 72 + ks + fq * 8];
                acc[0][j] = mfma16(a0, bj, acc[0][j]);
                acc[1][j] = mfma16(a1, bj, acc[1][j]);
            }
        }
    }
    __syncthreads();   // frag reads done; reuse Bsl as [l][o] staging
#pragma unroll
    for (int i = 0; i < 2; ++i)
#pragma unroll
        for (int r = 0; r < 4; ++r) {
            int row = m0 + i * 16 + fq * 4 + r;
            float bias = bsk[layer * HH + row];
#pragma unroll
            for (int j = 0; j < 4; ++j) {
                float v = gelu_fast(acc[i][j][r] + bias);
                int lc = n0 + j * 16 + fm;
                Bsl[lc * 72 + row] = (f16)v;
            }
        }
    __syncthreads();
    {   // write XTn[b][l][o] vectorized
        int row = t >> 1, half = t & 1;
        f16* dst = XTn + ((size_t)b * LL + l0 + row) * HH + half * 32;
        const f16* src = &Bsl[row * 72 + half * 32];
#pragma unroll
        for (int i = 0; i < 4; ++i)
            F4(dst + i * 8) = CF4(src + i * 8);
    }
}

// ---------------------------------------------------------------------------
// Final layer (i=3) + projection, only l = L-1. grid 32 (b), block 128.
// ---------------------------------------------------------------------------
__global__ __launch_bounds__(128) void k_final(const f16* __restrict__ Ofh,
                                               const f16* __restrict__ XT3,
                                               const f16* __restrict__ Ttr,
                                               const float* __restrict__ wsk,
                                               const float* __restrict__ bsk,
                                               const float* __restrict__ wp1,
                                               const float* __restrict__ bp1,
                                               const float* __restrict__ wp2,
                                               const float* __restrict__ bp2,
                                               float* __restrict__ out) {
    __shared__ float ofs[64 * 129];    // Of[b] fp32, pitch 129
    __shared__ float wsks[64 * 65];    // w_skip[3], pitch 65
    __shared__ float wp1s[128 * 65];   // w_p1, pitch 65
    __shared__ float tl[128], xl[64], x4[64], y[128];
    const int b = blockIdx.x, t = threadIdx.x;
    {   // Of[b]: 8192 f16 coalesced
#pragma unroll
        for (int i = 0; i < 8; ++i) {
            int g = t + i * 128;
            f16x8 v = *(const f16x8*)(Ofh + (size_t)b * HH * 128 + g * 8);
            int o = g >> 4, k0 = (g & 15) * 8;
#pragma unroll
            for (int e = 0; e < 8; ++e) ofs[o * 129 + k0 + e] = (float)v[e];
        }
    }
    {   // wsk[3]: 4096 f32
        const float* src = wsk + 3 * HH * HH;
#pragma unroll
        for (int i = 0; i < 8; ++i) {
            int g = t + i * 128;
            float4 v = CF4(src + g * 4);
            int o = g >> 4, c0 = (g & 15) * 4;
            F4(&wsks[o * 65 + c0]) = v;
        }
    }
    {   // wp1: 8192 f32
#pragma unroll
        for (int i = 0; i < 16; ++i) {
            int g = t + i * 128;
            float4 v = CF4(wp1 + g * 4);
            int p = g >> 4, c0 = (g & 15) * 4;
            F4(&wp1s[p * 65 + c0]) = v;
        }
    }
    tl[t] = (float)Ttr[(size_t)(LL - 1) * 128 + t];
    if (t < 64) xl[t] = (float)XT3[((size_t)b * LL + (LL - 1)) * HH + t];
    __syncthreads();
    if (t < 64) {
        const int o = t;
        float acc = bsk[3 * HH + o];
        for (int k = 0; k < 128; ++k) acc += ofs[o * 129 + k] * tl[k];
        for (int i = 0; i < 64; ++i) acc += wsks[o * 65 + i] * xl[i];
        x4[o] = acc;   // no gelu after last FNO layer
    }
    __syncthreads();
    {
        float acc = bp1[t];
        for (int h = 0; h < 64; ++h) acc += wp1s[t * 65 + h] * x4[h];
        y[t] = gelu_fast(acc);
    }
    __syncthreads();
    if (t < 8) {
        float acc = bp2[t];
        for (int p = 0; p < 128; ++p) acc += wp2[t * 128 + p] * y[p];
        out[b * 8 + t] = acc;   // float32 output
    }
}

// ---------------------------------------------------------------------------
extern "C" void kernel_launch(void* const* d_in, const int* in_sizes, int n_in,
                              void* d_out, int out_size, void* d_ws, size_t ws_size,
                              hipStream_t stream) {
    (void)in_sizes; (void)n_in; (void)out_size; (void)ws_size;
    const float* u   = (const float*)d_in[0];
    const float* z   = (const float*)d_in[1];
    // d_in[2] = t, unused by the reference
    const float* wl  = (const float*)d_in[3];
    const float* bl  = (const float*)d_in[4];
    const float* swr = (const float*)d_in[5];
    const float* swi = (const float*)d_in[6];
    const float* wsk = (const float*)d_in[7];
    const float* bsk = (const float*)d_in[8];
    const float* wp1 = (const float*)d_in[9];
    const float* bp1 = (const float*)d_in[10];
    const float* wp2 = (const float*)d_in[11];
    const float* bp2 = (const float*)d_in[12];
    float* out = (float*)d_out;

    f16* ws    = (f16*)d_ws;
    f16* XTa   = ws;                  // 8,388,608 h (16 MB)  [b][l][h]
    f16* XTb   = XTa + 8388608;       // 8,388,608 h
    f16* Tdt   = XTb + 8388608;       //   524,288 h  [m2][l]
    f16* Ttr   = Tdt + 524288;        //   524,288 h  [l][m2]
    f16* Ofh   = Ttr + 524288;        //   262,144 h  [b][o][m2]
    f16* wskh  = Ofh + 262144;        //    16,384 h
    f16* wrh   = wskh + 16384;        // 1,048,576 h
    f16* wih   = wrh + 1048576;       // 1,048,576 h
    // total ~40 MB

    k_init<<<2560, 256, 0, stream>>>(u, z, wl, bl, wsk, swr, swi,
                                     Tdt, Ttr, wskh, wrh, wih, XTa);

    f16* xtc = XTa; f16* xtn = XTb;
    for (int layer = 0; layer < 4; ++layer) {
        k_dftspec<<<64, 1024, 0, stream>>>(xtc, Tdt, wrh, wih, Ofh, layer);
        if (layer < 3) {
            k_recon<<<dim3(32, 32), 256, 0, stream>>>(Ofh, xtc, Ttr, wskh, bsk,
                                                      xtn, layer);
            f16* tmp = xtc; xtc = xtn; xtn = tmp;
        } else {
            k_final<<<32, 128, 0, stream>>>(Ofh, xtc, Ttr, wsk, bsk,
                                            wp1, bp1, wp2, bp2, out);
        }
    }
}

// Round 9
// 268.939 us; speedup vs baseline: 6.0525x; 1.1789x over previous
//
#include <hip/hip_runtime.h>
#include <math.h>

typedef _Float16 f16;
typedef f16  f16x2 __attribute__((ext_vector_type(2)));
typedef f16  f16x4 __attribute__((ext_vector_type(4)));
typedef f16  f16x8 __attribute__((ext_vector_type(8)));
typedef float f32x4 __attribute__((ext_vector_type(4)));

#define F4(p)  (*(float4*)(p))
#define CF4(p) (*(const float4*)(p))

namespace {
constexpr int LL = 4096;   // sequence
constexpr int HH = 64;     // channels

__device__ __forceinline__ float gelu_fast(float x) {
    // 0.5x(1+tanh(i)) == x*sigmoid(2i); exp-neg form is NaN-free at +/-inf
    float inner = 0.7978845608028654f * (x + 0.044715f * x * x * x);
    float e = __expf(-2.0f * inner);
    return x / (1.0f + e);
}

__device__ __forceinline__ f32x4 mfma16(f16x8 a, f16x8 b, f32x4 c) {
    return __builtin_amdgcn_mfma_f32_16x16x32_f16(a, b, c, 0, 0, 0);
}
} // namespace

// ---------------------------------------------------------------------------
// k_init: fused lift [0,512) + twiddle [512,1536) + wr/wi fp16 cvt [1536,2560)
//   Tdt[m2][l]:  cos(2pi m l/L), -sin               (DFT weights, f16)
//   Ttr[l][m2]: (m==0?1:2cos)/L, (m==0?0:-2sin)/L   (irfft weights, f16)
// (verbatim from round-5 / 214 us baseline)
// ---------------------------------------------------------------------------
__global__ __launch_bounds__(256) void k_init(const float* __restrict__ u,
                                              const float* __restrict__ z,
                                              const float* __restrict__ wl,
                                              const float* __restrict__ bl,
                                              const float* __restrict__ wsk,
                                              const float* __restrict__ wr,
                                              const float* __restrict__ wi,
                                              f16* __restrict__ Tdt,
                                              f16* __restrict__ Ttr,
                                              f16* __restrict__ wskh,
                                              f16* __restrict__ wrh,
                                              f16* __restrict__ wih,
                                              f16* __restrict__ XT0) {
    const int bid = blockIdx.x;
    const int t = threadIdx.x;
    if (bid < 512) {
        // ---- lift: XT0[b][l][h], register-tiled 8h x 8l per thread
        const int b = bid >> 4;
        const int l0 = (bid & 15) * 256;
        constexpr int IP = 260;
        __shared__ float in_s[16 * IP];
        __shared__ float wsh[64 * 16];
        __shared__ float bsh[64];
        for (int i = t; i < 1024; i += 256) wsh[i] = wl[i];
        if (t < 64) bsh[t] = bl[t];
#pragma unroll
        for (int q = 0; q < 2; ++q) {
            int f = t + q * 256;
            int l = f >> 1, cq = (f & 1) * 4;
            float4 v = CF4(u + ((size_t)b * LL + l0 + l) * 8 + cq);
            in_s[(cq + 0) * IP + l] = v.x;
            in_s[(cq + 1) * IP + l] = v.y;
            in_s[(cq + 2) * IP + l] = v.z;
            in_s[(cq + 3) * IP + l] = v.w;
        }
        for (int f = t; f < 8 * 256; f += 256) {
            int c = f >> 8, l = f & 255;
            in_s[(8 + c) * IP + l] = z[b * 8 + c];
        }
        __syncthreads();
        const int hg = t >> 5, lsub = t & 31;
        float acc[8][8] = {};
        for (int c = 0; c < 16; ++c) {
            float wv[8], inv[8];
#pragma unroll
            for (int i = 0; i < 8; ++i) wv[i] = wsh[(hg * 8 + i) * 16 + c];
#pragma unroll
            for (int j = 0; j < 8; ++j) inv[j] = in_s[c * IP + lsub + 32 * j];
#pragma unroll
            for (int i = 0; i < 8; ++i)
#pragma unroll
                for (int j = 0; j < 8; ++j) acc[i][j] += wv[i] * inv[j];
        }
#pragma unroll
        for (int j = 0; j < 8; ++j) {
            __attribute__((aligned(16))) f16 hv[8];
#pragma unroll
            for (int i = 0; i < 8; ++i) hv[i] = (f16)(acc[i][j] + bsh[hg * 8 + i]);
            int l = l0 + lsub + 32 * j;
            F4(XT0 + ((size_t)b * LL + l) * HH + hg * 8) = CF4(hv);
        }
    } else if (bid < 1536) {
        // ---- twiddle (both orientations coalesced)
        const int tb = bid - 512;
        const float w0 = 6.283185307179586f / 4096.0f;
        {   // Tdt: lane runs along l
            int m = tb >> 4;
            int l = ((tb & 15) << 8) + t;
            float s, c;
            sincosf((float)((l * m) & 4095) * w0, &s, &c);
            Tdt[(size_t)(2 * m) * LL + l]     = (f16)c;
            Tdt[(size_t)(2 * m + 1) * LL + l] = (f16)(-s);
        }
        {   // Ttr: lane runs along m2 (4B per lane)
            int l = tb * 4 + (t >> 6);
            int m = t & 63;
            float s, c;
            sincosf((float)((l * m) & 4095) * w0, &s, &c);
            const float sc = 1.0f / 4096.0f;
            f16x2 pv;
            pv.x = (f16)((m == 0) ? sc : 2.0f * sc * c);
            pv.y = (f16)((m == 0) ? 0.0f : -2.0f * sc * s);
            *(f16x2*)(Ttr + (size_t)l * 128 + 2 * m) = pv;
        }
        if (tb < 64) {
            int idx = tb * 256 + t;
            wskh[idx] = (f16)wsk[idx];
        }
    } else {
        // ---- wr/wi -> f16 (4 elements each per thread)
        const int cb = bid - 1536;
        size_t base = (size_t)cb * 1024 + t * 4;
        float4 vr = CF4(wr + base);
        float4 vi = CF4(wi + base);
        f16x4 hr, hi;
        hr.x = (f16)vr.x; hr.y = (f16)vr.y; hr.z = (f16)vr.z; hr.w = (f16)vr.w;
        hi.x = (f16)vi.x; hi.y = (f16)vi.y; hi.z = (f16)vi.z; hi.w = (f16)vi.w;
        *(f16x4*)(wrh + base) = hr;
        *(f16x4*)(wih + base) = hi;
    }
}

// ---------------------------------------------------------------------------
// Partial DFT, fp16 MFMA, M=32 split (2 blocks/CU), REGISTER-PREFETCHED:
//   Y[ch][(b,h)][m2] = sum_{l in 512-chunk} XT[b][l][h] * Tdt[m2][l]   (f16 out)
// grid (16 = ch*2+hhalf, 32 b), block 256 (4 waves). Tile 32 h x 128 m2, K=512.
// Next chunk's global loads issue during compute (latency overlapped).
// ---------------------------------------------------------------------------
__global__ __launch_bounds__(256) void k_dft(const f16* __restrict__ XT,
                                             const f16* __restrict__ Tdt,
                                             f16* __restrict__ Y) {
    __shared__ f16 Asl[32 * 72];    // [h][l-chunk] pitch 72
    __shared__ f16 Bsl[128 * 72];   // [m2][l-chunk] pitch 72
    const int t = threadIdx.x;
    const int ch = blockIdx.x >> 1, h0 = (blockIdx.x & 1) * 32, b = blockIdx.y;
    const int lane = t & 63, wid = t >> 6;
    const int mh = (wid & 1) * 16, n0 = (wid >> 1) * 64;
    const int fm = lane & 15, fq = lane >> 4;
    const int seg = t >> 6;           // A-staging: 4 segs x 8 h
    const int br = t >> 3, bs = t & 7; // B-staging: rows x 8-f16 segs
    const int l0base = ch * 512;
    f32x4 acc[4] = {};
    // prefetch chunk 0
    f16x8 ra = *(const f16x8*)(XT + ((size_t)b * LL + l0base + lane) * HH + h0 + seg * 8);
    float4 rb[4];
#pragma unroll
    for (int p = 0; p < 4; ++p)
        rb[p] = CF4(Tdt + (size_t)(br + p * 32) * LL + l0base + bs * 8);
    for (int k0 = 0; k0 < 512; k0 += 64) {
        __syncthreads();
        {   // A: regs -> Asl[h][l] transpose (2-way LDS alias: free)
#pragma unroll
            for (int i = 0; i < 8; ++i) Asl[(seg * 8 + i) * 72 + lane] = ra[i];
        }
#pragma unroll
        for (int p = 0; p < 4; ++p)    // B: regs -> Bsl
            F4(&Bsl[(br + p * 32) * 72 + bs * 8]) = rb[p];
        __syncthreads();
        if (k0 < 448) {   // prefetch next chunk while MFMAs run
            int l0 = l0base + k0 + 64;
            ra = *(const f16x8*)(XT + ((size_t)b * LL + l0 + lane) * HH + h0 + seg * 8);
#pragma unroll
            for (int p = 0; p < 4; ++p)
                rb[p] = CF4(Tdt + (size_t)(br + p * 32) * LL + l0 + bs * 8);
        }
#pragma unroll
        for (int ks = 0; ks < 64; ks += 32) {
            f16x8 a = *(const f16x8*)&Asl[(mh + fm) * 72 + ks + fq * 8];
#pragma unroll
            for (int j = 0; j < 4; ++j) {
                f16x8 bj = *(const f16x8*)&Bsl[(n0 + j * 16 + fm) * 72 + ks + fq * 8];
                acc[j] = mfma16(a, bj, acc[j]);
            }
        }
    }
    f16* yp = Y + ((size_t)ch * 2048 + b * HH + h0) * 128;
#pragma unroll
    for (int j = 0; j < 4; ++j)
#pragma unroll
        for (int r = 0; r < 4; ++r)
            yp[(size_t)(mh + fq * 4 + r) * 128 + n0 + j * 16 + fm] = (f16)acc[j][r];
}

// ---------------------------------------------------------------------------
// Spectral mix + split-K reduce. grid (32 b, 8 og) -> 256 blocks; each block
// computes 8 o's (2 per thread) => Y staging redundancy halved vs 16-og.
// XCD = b%8 via blockIdx.x = b (Y slice and weights L2-local).
// fp32 math, f16 in/out; ascending-ch sum order (deterministic, = R5).
// ---------------------------------------------------------------------------
__global__ __launch_bounds__(256) void k_spec(const f16* __restrict__ Y,
                                              const f16* __restrict__ wrh,
                                              const f16* __restrict__ wih,
                                              f16* __restrict__ Ofh, int layer) {
    __shared__ float xsh[64 * 128];
    const int t = threadIdx.x;
    const int b = blockIdx.x;
    const int og = blockIdx.y;   // 0..7
    {   // stage Xf[b] = sum_ch Y[ch][b]  (ascending ch, fp32 accum)
#pragma unroll
        for (int i = 0; i < 4; ++i) {
            int g = t + i * 256;            // f16x8 group, 1024 total
            float s[8] = {};
#pragma unroll
            for (int c = 0; c < 8; ++c) {
                f16x8 v = *(const f16x8*)(Y + ((size_t)c * 2048 + b * HH) * 128 + g * 8);
#pragma unroll
                for (int e = 0; e < 8; ++e) s[e] += (float)v[e];
            }
#pragma unroll
            for (int e = 0; e < 8; ++e) xsh[g * 8 + e] = s[e];
        }
    }
    __syncthreads();
    const int m = t & 63, osub = t >> 6;
    const int o0 = og * 8 + osub;           // and o0 + 4
    const f16* wr0 = wrh + ((size_t)layer * HH + o0) * HH * 64 + m;
    const f16* wi0 = wih + ((size_t)layer * HH + o0) * HH * 64 + m;
    const f16* wr1 = wr0 + (size_t)4 * HH * 64;
    const f16* wi1 = wi0 + (size_t)4 * HH * 64;
    float are0 = 0, aim0 = 0, are1 = 0, aim1 = 0;
    const float2* xs2 = (const float2*)xsh;
#pragma unroll 8
    for (int i = 0; i < 64; ++i) {
        float2 xv = xs2[i * 64 + m];
        float w0r = (float)wr0[(size_t)i * 64], w0i = (float)wi0[(size_t)i * 64];
        float w1r = (float)wr1[(size_t)i * 64], w1i = (float)wi1[(size_t)i * 64];
        are0 += xv.x * w0r - xv.y * w0i;  aim0 += xv.x * w0i + xv.y * w0r;
        are1 += xv.x * w1r - xv.y * w1i;  aim1 += xv.x * w1i + xv.y * w1r;
    }
    f16x2 ov0; ov0.x = (f16)are0; ov0.y = (f16)aim0;
    f16x2 ov1; ov1.x = (f16)are1; ov1.y = (f16)aim1;
    *(f16x2*)(Ofh + ((size_t)b * HH + o0) * 128 + 2 * m)     = ov0;
    *(f16x2*)(Ofh + ((size_t)b * HH + o0 + 4) * 128 + 2 * m) = ov1;
}

// ---------------------------------------------------------------------------
// Recon (layers 0..2), fp16 MFMA, fused K=192 = [Of | Wsk] x [Ttr ; X^T]:
//   x_next[b][o][l] = gelu( sum_k A[o][k]*B[k][l] + bsk[o] )
// Output in transposed layout XTn[b][l][o] (via LDS transpose).
// grid (32 l-tiles of 128, 32 b), block 256 (4 waves), tile 64 o x 128 l.
// (verbatim from round-5 / 214 us baseline)
// ---------------------------------------------------------------------------
__global__ __launch_bounds__(256) void k_recon(const f16* __restrict__ Ofh,
                                               const f16* __restrict__ XT,
                                               const f16* __restrict__ Ttr,
                                               const f16* __restrict__ wskh,
                                               const float* __restrict__ bsk,
                                               f16* __restrict__ XTn,
                                               int layer) {
    __shared__ f16 Asl[64 * 200];   // [o][k 0..191], pitch 200
    __shared__ f16 Bsl[128 * 72];   // [l][k-chunk], pitch 72; reused for transpose
    const int t = threadIdx.x;
    const int l0 = blockIdx.x * 128, b = blockIdx.y;
    const int lane = t & 63, wid = t >> 6;
    const int m0 = (wid & 1) * 32, n0 = (wid >> 1) * 64;
    const int fm = lane & 15, fq = lane >> 4;
    f32x4 acc[2][4] = {};
    {   // stage A = [Of[b] | wskh[layer]]
        int seg = t & 15, row = t >> 4;
#pragma unroll
        for (int p = 0; p < 4; ++p) {
            int r = row + p * 16;
            F4(&Asl[r * 200 + seg * 8]) = CF4(Ofh + ((size_t)(b * HH + r)) * 128 + seg * 8);
        }
        int seg8 = t & 7, row8 = t >> 3;
#pragma unroll
        for (int p = 0; p < 2; ++p) {
            int r = row8 + p * 32;
            F4(&Asl[r * 200 + 128 + seg8 * 8]) =
                CF4(wskh + ((size_t)(layer * HH + r)) * HH + seg8 * 8);
        }
    }
    const int srow = t >> 3, sseg = t & 7;
    for (int k0 = 0; k0 < 192; k0 += 64) {
        __syncthreads();
#pragma unroll
        for (int p = 0; p < 4; ++p) {   // B rows l: Ttr[l][k0..] or XT[b][l][h]
            int r = srow + p * 32;
            const f16* src = (k0 < 128)
                ? (Ttr + (size_t)(l0 + r) * 128 + k0 + sseg * 8)
                : (XT + ((size_t)b * LL + l0 + r) * HH + sseg * 8);
            F4(&Bsl[r * 72 + sseg * 8]) = CF4(src);
        }
        __syncthreads();
#pragma unroll
        for (int ks = 0; ks < 64; ks += 32) {
            f16x8 a0 = *(const f16x8*)&Asl[(m0 + fm) * 200 + k0 + ks + fq * 8];
            f16x8 a1 = *(const f16x8*)&Asl[(m0 + 16 + fm) * 200 + k0 + ks + fq * 8];
#pragma unroll
            for (int j = 0; j < 4; ++j) {
                f16x8 bj = *(const f16x8*)&Bsl[(n0 + j * 16 + fm) * 72 + ks + fq * 8];
                acc[0][j] = mfma16(a0, bj, acc[0][j]);
                acc[1][j] = mfma16(a1, bj, acc[1][j]);
            }
        }
    }
    __syncthreads();   // frag reads done; reuse Bsl as [l][o] staging
#pragma unroll
    for (int i = 0; i < 2; ++i)
#pragma unroll
        for (int r = 0; r < 4; ++r) {
            int row = m0 + i * 16 + fq * 4 + r;
            float bias = bsk[layer * HH + row];
#pragma unroll
            for (int j = 0; j < 4; ++j) {
                float v = gelu_fast(acc[i][j][r] + bias);
                int lc = n0 + j * 16 + fm;
                Bsl[lc * 72 + row] = (f16)v;
            }
        }
    __syncthreads();
    {   // write XTn[b][l][o] vectorized
        int row = t >> 1, half = t & 1;
        f16* dst = XTn + ((size_t)b * LL + l0 + row) * HH + half * 32;
        const f16* src = &Bsl[row * 72 + half * 32];
#pragma unroll
        for (int i = 0; i < 4; ++i)
            F4(dst + i * 8) = CF4(src + i * 8);
    }
}

// ---------------------------------------------------------------------------
// Final layer (i=3) + projection, only l = L-1. grid 32 (b), block 128.
// (verbatim from round-5 / 214 us baseline)
// ---------------------------------------------------------------------------
__global__ __launch_bounds__(128) void k_final(const f16* __restrict__ Ofh,
                                               const f16* __restrict__ XT3,
                                               const f16* __restrict__ Ttr,
                                               const float* __restrict__ wsk,
                                               const float* __restrict__ bsk,
                                               const float* __restrict__ wp1,
                                               const float* __restrict__ bp1,
                                               const float* __restrict__ wp2,
                                               const float* __restrict__ bp2,
                                               float* __restrict__ out) {
    __shared__ float ofs[64 * 129];    // Of[b] fp32, pitch 129
    __shared__ float wsks[64 * 65];    // w_skip[3], pitch 65
    __shared__ float wp1s[128 * 65];   // w_p1, pitch 65
    __shared__ float tl[128], xl[64], x4[64], y[128];
    const int b = blockIdx.x, t = threadIdx.x;
    {   // Of[b]: 8192 f16 coalesced
#pragma unroll
        for (int i = 0; i < 8; ++i) {
            int g = t + i * 128;
            f16x8 v = *(const f16x8*)(Ofh + (size_t)b * HH * 128 + g * 8);
            int o = g >> 4, k0 = (g & 15) * 8;
#pragma unroll
            for (int e = 0; e < 8; ++e) ofs[o * 129 + k0 + e] = (float)v[e];
        }
    }
    {   // wsk[3]: 4096 f32
        const float* src = wsk + 3 * HH * HH;
#pragma unroll
        for (int i = 0; i < 8; ++i) {
            int g = t + i * 128;
            float4 v = CF4(src + g * 4);
            int o = g >> 4, c0 = (g & 15) * 4;
            F4(&wsks[o * 65 + c0]) = v;
        }
    }
    {   // wp1: 8192 f32
#pragma unroll
        for (int i = 0; i < 16; ++i) {
            int g = t + i * 128;
            float4 v = CF4(wp1 + g * 4);
            int p = g >> 4, c0 = (g & 15) * 4;
            F4(&wp1s[p * 65 + c0]) = v;
        }
    }
    tl[t] = (float)Ttr[(size_t)(LL - 1) * 128 + t];
    if (t < 64) xl[t] = (float)XT3[((size_t)b * LL + (LL - 1)) * HH + t];
    __syncthreads();
    if (t < 64) {
        const int o = t;
        float acc = bsk[3 * HH + o];
        for (int k = 0; k < 128; ++k) acc += ofs[o * 129 + k] * tl[k];
        for (int i = 0; i < 64; ++i) acc += wsks[o * 65 + i] * xl[i];
        x4[o] = acc;   // no gelu after last FNO layer
    }
    __syncthreads();
    {
        float acc = bp1[t];
        for (int h = 0; h < 64; ++h) acc += wp1s[t * 65 + h] * x4[h];
        y[t] = gelu_fast(acc);
    }
    __syncthreads();
    if (t < 8) {
        float acc = bp2[t];
        for (int p = 0; p < 128; ++p) acc += wp2[t * 128 + p] * y[p];
        out[b * 8 + t] = acc;   // float32 output
    }
}

// ---------------------------------------------------------------------------
extern "C" void kernel_launch(void* const* d_in, const int* in_sizes, int n_in,
                              void* d_out, int out_size, void* d_ws, size_t ws_size,
                              hipStream_t stream) {
    (void)in_sizes; (void)n_in; (void)out_size; (void)ws_size;
    const float* u   = (const float*)d_in[0];
    const float* z   = (const float*)d_in[1];
    // d_in[2] = t, unused by the reference
    const float* wl  = (const float*)d_in[3];
    const float* bl  = (const float*)d_in[4];
    const float* swr = (const float*)d_in[5];
    const float* swi = (const float*)d_in[6];
    const float* wsk = (const float*)d_in[7];
    const float* bsk = (const float*)d_in[8];
    const float* wp1 = (const float*)d_in[9];
    const float* bp1 = (const float*)d_in[10];
    const float* wp2 = (const float*)d_in[11];
    const float* bp2 = (const float*)d_in[12];
    float* out = (float*)d_out;

    f16* ws    = (f16*)d_ws;
    f16* XTa   = ws;                  // 8,388,608 h (16 MB)  [b][l][h]
    f16* XTb   = XTa + 8388608;       // 8,388,608 h
    f16* Tdt   = XTb + 8388608;       //   524,288 h  [m2][l]
    f16* Ttr   = Tdt + 524288;        //   524,288 h  [l][m2]
    f16* Ofh   = Ttr + 524288;        //   262,144 h  [b][o][m2]
    f16* wskh  = Ofh + 262144;        //    16,384 h
    f16* wrh   = wskh + 16384;        // 1,048,576 h
    f16* wih   = wrh + 1048576;       // 1,048,576 h
    // total ~40 MB. Y (4 MB f16 split-K partials) overlays the dead XT buffer.

    k_init<<<2560, 256, 0, stream>>>(u, z, wl, bl, wsk, swr, swi,
                                     Tdt, Ttr, wskh, wrh, wih, XTa);

    f16* xtc = XTa; f16* xtn = XTb;
    for (int layer = 0; layer < 4; ++layer) {
        f16* Y = xtn;   // dead until recon writes XTn (spec consumes Y first)
        k_dft<<<dim3(16, 32), 256, 0, stream>>>(xtc, Tdt, Y);
        k_spec<<<dim3(32, 8), 256, 0, stream>>>(Y, wrh, wih, Ofh, layer);
        if (layer < 3) {
            k_recon<<<dim3(32, 32), 256, 0, stream>>>(Ofh, xtc, Ttr, wskh, bsk,
                                                      xtn, layer);
            f16* tmp = xtc; xtc = xtn; xtn = tmp;
        } else {
            k_final<<<32, 128, 0, stream>>>(Ofh, xtc, Ttr, wsk, bsk,
                                            wp1, bp1, wp2, bp2, out);
        }
    }
}

// Round 10
// 212.566 us; speedup vs baseline: 7.6577x; 1.2652x over previous
//
#include <hip/hip_runtime.h>
#include <math.h>

typedef _Float16 f16;
typedef f16  f16x2 __attribute__((ext_vector_type(2)));
typedef f16  f16x4 __attribute__((ext_vector_type(4)));
typedef f16  f16x8 __attribute__((ext_vector_type(8)));
typedef float f32x4 __attribute__((ext_vector_type(4)));

#define F4(p)  (*(float4*)(p))
#define CF4(p) (*(const float4*)(p))

namespace {
constexpr int LL = 4096;   // sequence
constexpr int HH = 64;     // channels

__device__ __forceinline__ float gelu_fast(float x) {
    // 0.5x(1+tanh(i)) == x*sigmoid(2i); exp-neg form is NaN-free at +/-inf
    float inner = 0.7978845608028654f * (x + 0.044715f * x * x * x);
    float e = __expf(-2.0f * inner);
    return x / (1.0f + e);
}

__device__ __forceinline__ f32x4 mfma16(f16x8 a, f16x8 b, f32x4 c) {
    return __builtin_amdgcn_mfma_f32_16x16x32_f16(a, b, c, 0, 0, 0);
}
} // namespace

// ---------------------------------------------------------------------------
// k_init: fused lift [0,512) + twiddle [512,1536) + wr/wi fp16 cvt [1536,2560)
//   Tdt[m2][l]:  cos(2pi m l/L), -sin                (DFT weights, f16)
//   Ttr[l][m2]: (m==0?1:2cos)/L, (m==0?0:-2sin)/L    (irfft weights, f16)
// Both tables written COALESCED (lane runs along the contiguous dim).
// ---------------------------------------------------------------------------
__global__ __launch_bounds__(256) void k_init(const float* __restrict__ u,
                                              const float* __restrict__ z,
                                              const float* __restrict__ wl,
                                              const float* __restrict__ bl,
                                              const float* __restrict__ wsk,
                                              const float* __restrict__ wr,
                                              const float* __restrict__ wi,
                                              f16* __restrict__ Tdt,
                                              f16* __restrict__ Ttr,
                                              f16* __restrict__ wskh,
                                              f16* __restrict__ wrh,
                                              f16* __restrict__ wih,
                                              f16* __restrict__ XT0) {
    const int bid = blockIdx.x;
    const int t = threadIdx.x;
    if (bid < 512) {
        // ---- lift: XT0[b][l][h], register-tiled 8h x 8l per thread
        const int b = bid >> 4;
        const int l0 = (bid & 15) * 256;
        constexpr int IP = 260;
        __shared__ float in_s[16 * IP];
        __shared__ float wsh[64 * 16];
        __shared__ float bsh[64];
        for (int i = t; i < 1024; i += 256) wsh[i] = wl[i];
        if (t < 64) bsh[t] = bl[t];
#pragma unroll
        for (int q = 0; q < 2; ++q) {
            int f = t + q * 256;
            int l = f >> 1, cq = (f & 1) * 4;
            float4 v = CF4(u + ((size_t)b * LL + l0 + l) * 8 + cq);
            in_s[(cq + 0) * IP + l] = v.x;
            in_s[(cq + 1) * IP + l] = v.y;
            in_s[(cq + 2) * IP + l] = v.z;
            in_s[(cq + 3) * IP + l] = v.w;
        }
        for (int f = t; f < 8 * 256; f += 256) {
            int c = f >> 8, l = f & 255;
            in_s[(8 + c) * IP + l] = z[b * 8 + c];
        }
        __syncthreads();
        const int hg = t >> 5, lsub = t & 31;
        float acc[8][8] = {};
        for (int c = 0; c < 16; ++c) {
            float wv[8], inv[8];
#pragma unroll
            for (int i = 0; i < 8; ++i) wv[i] = wsh[(hg * 8 + i) * 16 + c];
#pragma unroll
            for (int j = 0; j < 8; ++j) inv[j] = in_s[c * IP + lsub + 32 * j];
#pragma unroll
            for (int i = 0; i < 8; ++i)
#pragma unroll
                for (int j = 0; j < 8; ++j) acc[i][j] += wv[i] * inv[j];
        }
#pragma unroll
        for (int j = 0; j < 8; ++j) {
            __attribute__((aligned(16))) f16 hv[8];
#pragma unroll
            for (int i = 0; i < 8; ++i) hv[i] = (f16)(acc[i][j] + bsh[hg * 8 + i]);
            int l = l0 + lsub + 32 * j;
            F4(XT0 + ((size_t)b * LL + l) * HH + hg * 8) = CF4(hv);
        }
    } else if (bid < 1536) {
        // ---- twiddle (both orientations coalesced)
        const int tb = bid - 512;
        const float w0 = 6.283185307179586f / 4096.0f;
        {   // Tdt: lane runs along l
            int m = tb >> 4;
            int l = ((tb & 15) << 8) + t;
            float s, c;
            sincosf((float)((l * m) & 4095) * w0, &s, &c);
            Tdt[(size_t)(2 * m) * LL + l]     = (f16)c;
            Tdt[(size_t)(2 * m + 1) * LL + l] = (f16)(-s);
        }
        {   // Ttr: lane runs along m2 (4B per lane)
            int l = tb * 4 + (t >> 6);
            int m = t & 63;
            float s, c;
            sincosf((float)((l * m) & 4095) * w0, &s, &c);
            const float sc = 1.0f / 4096.0f;
            f16x2 pv;
            pv.x = (f16)((m == 0) ? sc : 2.0f * sc * c);
            pv.y = (f16)((m == 0) ? 0.0f : -2.0f * sc * s);
            *(f16x2*)(Ttr + (size_t)l * 128 + 2 * m) = pv;
        }
        if (tb < 64) {
            int idx = tb * 256 + t;
            wskh[idx] = (f16)wsk[idx];
        }
    } else {
        // ---- wr/wi -> f16 (4 elements each per thread)
        const int cb = bid - 1536;
        size_t base = (size_t)cb * 1024 + t * 4;
        float4 vr = CF4(wr + base);
        float4 vi = CF4(wi + base);
        f16x4 hr, hi;
        hr.x = (f16)vr.x; hr.y = (f16)vr.y; hr.z = (f16)vr.z; hr.w = (f16)vr.w;
        hi.x = (f16)vi.x; hi.y = (f16)vi.y; hi.z = (f16)vi.z; hi.w = (f16)vi.w;
        *(f16x4*)(wrh + base) = hr;
        *(f16x4*)(wih + base) = hi;
    }
}

// ---------------------------------------------------------------------------
// Partial DFT, fp16 MFMA, M=32 split (2 blocks/CU):
//   Y[ch][(b,h)][m2] = sum_{l in 512-chunk} XT[b][l][h] * Tdt[m2][l]   (f16 out)
// grid (16 = ch*2+hhalf, 32 b), block 256 (4 waves). Tile 32 h x 128 m2, K=512.
// ---------------------------------------------------------------------------
__global__ __launch_bounds__(256) void k_dft(const f16* __restrict__ XT,
                                             const f16* __restrict__ Tdt,
                                             f16* __restrict__ Y) {
    __shared__ f16 Asl[32 * 72];    // [h][l-chunk] pitch 72
    __shared__ f16 Bsl[128 * 72];   // [m2][l-chunk] pitch 72
    const int t = threadIdx.x;
    const int ch = blockIdx.x >> 1, h0 = (blockIdx.x & 1) * 32, b = blockIdx.y;
    const int lane = t & 63, wid = t >> 6;
    const int mh = (wid & 1) * 16, n0 = (wid >> 1) * 64;
    const int fm = lane & 15, fq = lane >> 4;
    f32x4 acc[4] = {};
    for (int k0 = 0; k0 < 512; k0 += 64) {
        const int l0 = ch * 512 + k0;
        __syncthreads();
        {   // A: XT[b][l][h0..h0+32] -> Asl[h][l] (LDS transpose, 2-way free)
            int seg = t >> 6;   // 4 segs x 8 h
            f16x8 v = *(const f16x8*)(XT + ((size_t)b * LL + l0 + lane) * HH + h0 + seg * 8);
#pragma unroll
            for (int i = 0; i < 8; ++i) Asl[(seg * 8 + i) * 72 + lane] = v[i];
        }
#pragma unroll
        for (int p = 0; p < 4; ++p) {   // B: Tdt[m2][l0..l0+63]
            int r = (t >> 3) + p * 32;
            F4(&Bsl[r * 72 + (t & 7) * 8]) = CF4(Tdt + (size_t)r * LL + l0 + (t & 7) * 8);
        }
        __syncthreads();
#pragma unroll
        for (int ks = 0; ks < 64; ks += 32) {
            f16x8 a = *(const f16x8*)&Asl[(mh + fm) * 72 + ks + fq * 8];
#pragma unroll
            for (int j = 0; j < 4; ++j) {
                f16x8 bj = *(const f16x8*)&Bsl[(n0 + j * 16 + fm) * 72 + ks + fq * 8];
                acc[j] = mfma16(a, bj, acc[j]);
            }
        }
    }
    f16* yp = Y + ((size_t)ch * 2048 + b * HH + h0) * 128;
#pragma unroll
    for (int j = 0; j < 4; ++j)
#pragma unroll
        for (int r = 0; r < 4; ++r)
            yp[(size_t)(mh + fq * 4 + r) * 128 + n0 + j * 16 + fm] = (f16)acc[j][r];
}

// ---------------------------------------------------------------------------
// Spectral mix + split-K reduce. grid (32 b, 16 og) -> XCD = b%8 (Y/weights
// become XCD-local). f16 Y and weights, fp32 math, f16 out.
// ---------------------------------------------------------------------------
__global__ __launch_bounds__(256) void k_spec(const f16* __restrict__ Y,
                                              const f16* __restrict__ wrh,
                                              const f16* __restrict__ wih,
                                              f16* __restrict__ Ofh, int layer) {
    __shared__ float xsh[64 * 128];
    const int t = threadIdx.x;
    const int b = blockIdx.x;
    const int og = blockIdx.y;
    {   // stage Xf[b] = sum_ch Y[ch][b]  (ascending ch, fp32 accum)
#pragma unroll
        for (int i = 0; i < 4; ++i) {
            int g = t + i * 256;            // f16x8 group, 1024 total
            float s[8] = {};
#pragma unroll
            for (int c = 0; c < 8; ++c) {
                f16x8 v = *(const f16x8*)(Y + ((size_t)c * 2048 + b * HH) * 128 + g * 8);
#pragma unroll
                for (int e = 0; e < 8; ++e) s[e] += (float)v[e];
            }
#pragma unroll
            for (int e = 0; e < 8; ++e) xsh[g * 8 + e] = s[e];
        }
    }
    __syncthreads();
    const int m = t & 63, osub = t >> 6;
    const int o = og * 4 + osub;
    const f16* wrp = wrh + ((size_t)layer * HH + o) * HH * 64 + m;
    const f16* wip = wih + ((size_t)layer * HH + o) * HH * 64 + m;
    float are = 0.0f, aim = 0.0f;
    const float2* xs2 = (const float2*)xsh;
#pragma unroll 8
    for (int i = 0; i < 64; ++i) {
        float2 xv = xs2[i * 64 + m];
        float wrv = (float)wrp[(size_t)i * 64];
        float wiv = (float)wip[(size_t)i * 64];
        are += xv.x * wrv - xv.y * wiv;
        aim += xv.x * wiv + xv.y * wrv;
    }
    f16x2 ov; ov.x = (f16)are; ov.y = (f16)aim;
    *(f16x2*)(Ofh + ((size_t)b * HH + o) * 128 + 2 * m) = ov;
}

// ---------------------------------------------------------------------------
// Recon (layers 0..2), fp16 MFMA, fused K=192 = [Of | Wsk] x [Ttr ; X^T]:
//   x_next[b][o][l] = gelu( sum_k A[o][k]*B[k][l] + bsk[o] )
// Output in transposed layout XTn[b][l][o] (via LDS transpose).
// grid (32 l-tiles of 128, 32 b), block 256 (4 waves), tile 64 o x 128 l.
// ---------------------------------------------------------------------------
__global__ __launch_bounds__(256) void k_recon(const f16* __restrict__ Ofh,
                                               const f16* __restrict__ XT,
                                               const f16* __restrict__ Ttr,
                                               const f16* __restrict__ wskh,
                                               const float* __restrict__ bsk,
                                               f16* __restrict__ XTn,
                                               int layer) {
    __shared__ f16 Asl[64 * 200];   // [o][k 0..191], pitch 200
    __shared__ f16 Bsl[128 * 72];   // [l][k-chunk], pitch 72; reused for transpose
    const int t = threadIdx.x;
    const int l0 = blockIdx.x * 128, b = blockIdx.y;
    const int lane = t & 63, wid = t >> 6;
    const int m0 = (wid & 1) * 32, n0 = (wid >> 1) * 64;
    const int fm = lane & 15, fq = lane >> 4;
    f32x4 acc[2][4] = {};
    {   // stage A = [Of[b] | wskh[layer]]
        int seg = t & 15, row = t >> 4;
#pragma unroll
        for (int p = 0; p < 4; ++p) {
            int r = row + p * 16;
            F4(&Asl[r * 200 + seg * 8]) = CF4(Ofh + ((size_t)(b * HH + r)) * 128 + seg * 8);
        }
        int seg8 = t & 7, row8 = t >> 3;
#pragma unroll
        for (int p = 0; p < 2; ++p) {
            int r = row8 + p * 32;
            F4(&Asl[r * 200 + 128 + seg8 * 8]) =
                CF4(wskh + ((size_t)(layer * HH + r)) * HH + seg8 * 8);
        }
    }
    const int srow = t >> 3, sseg = t & 7;
    for (int k0 = 0; k0 < 192; k0 += 64) {
        __syncthreads();
#pragma unroll
        for (int p = 0; p < 4; ++p) {   // B rows l: Ttr[l][k0..] or XT[b][l][h]
            int r = srow + p * 32;
            const f16* src = (k0 < 128)
                ? (Ttr + (size_t)(l0 + r) * 128 + k0 + sseg * 8)
                : (XT + ((size_t)b * LL + l0 + r) * HH + sseg * 8);
            F4(&Bsl[r * 72 + sseg * 8]) = CF4(src);
        }
        __syncthreads();
#pragma unroll
        for (int ks = 0; ks < 64; ks += 32) {
            f16x8 a0 = *(const f16x8*)&Asl[(m0 + fm) * 200 + k0 + ks + fq * 8];
            f16x8 a1 = *(const f16x8*)&Asl[(m0 + 16 + fm) * 200 + k0 + ks + fq * 8];
#pragma unroll
            for (int j = 0; j < 4; ++j) {
                f16x8 bj = *(const f16x8*)&Bsl[(n0 + j * 16 + fm) * 72 + ks + fq * 8];
                acc[0][j] = mfma16(a0, bj, acc[0][j]);
                acc[1][j] = mfma16(a1, bj, acc[1][j]);
            }
        }
    }
    __syncthreads();   // frag reads done; reuse Bsl as [l][o] staging
#pragma unroll
    for (int i = 0; i < 2; ++i)
#pragma unroll
        for (int r = 0; r < 4; ++r) {
            int row = m0 + i * 16 + fq * 4 + r;
            float bias = bsk[layer * HH + row];
#pragma unroll
            for (int j = 0; j < 4; ++j) {
                float v = gelu_fast(acc[i][j][r] + bias);
                int lc = n0 + j * 16 + fm;
                Bsl[lc * 72 + row] = (f16)v;
            }
        }
    __syncthreads();
    {   // write XTn[b][l][o] vectorized
        int row = t >> 1, half = t & 1;
        f16* dst = XTn + ((size_t)b * LL + l0 + row) * HH + half * 32;
        const f16* src = &Bsl[row * 72 + half * 32];
#pragma unroll
        for (int i = 0; i < 4; ++i)
            F4(dst + i * 8) = CF4(src + i * 8);
    }
}

// ---------------------------------------------------------------------------
// Final layer (i=3) + projection, only l = L-1. grid 32 (b), block 128.
// All operands LDS-staged with +1-padded pitches (conflict-free broadcasts).
// ---------------------------------------------------------------------------
__global__ __launch_bounds__(128) void k_final(const f16* __restrict__ Ofh,
                                               const f16* __restrict__ XT3,
                                               const f16* __restrict__ Ttr,
                                               const float* __restrict__ wsk,
                                               const float* __restrict__ bsk,
                                               const float* __restrict__ wp1,
                                               const float* __restrict__ bp1,
                                               const float* __restrict__ wp2,
                                               const float* __restrict__ bp2,
                                               float* __restrict__ out) {
    __shared__ float ofs[64 * 129];    // Of[b] fp32, pitch 129
    __shared__ float wsks[64 * 65];    // w_skip[3], pitch 65
    __shared__ float wp1s[128 * 65];   // w_p1, pitch 65
    __shared__ float tl[128], xl[64], x4[64], y[128];
    const int b = blockIdx.x, t = threadIdx.x;
    {   // Of[b]: 8192 f16 coalesced
#pragma unroll
        for (int i = 0; i < 8; ++i) {
            int g = t + i * 128;
            f16x8 v = *(const f16x8*)(Ofh + (size_t)b * HH * 128 + g * 8);
            int o = g >> 4, k0 = (g & 15) * 8;
#pragma unroll
            for (int e = 0; e < 8; ++e) ofs[o * 129 + k0 + e] = (float)v[e];
        }
    }
    {   // wsk[3]: 4096 f32
        const float* src = wsk + 3 * HH * HH;
#pragma unroll
        for (int i = 0; i < 8; ++i) {
            int g = t + i * 128;
            float4 v = CF4(src + g * 4);
            int o = g >> 4, c0 = (g & 15) * 4;
            F4(&wsks[o * 65 + c0]) = v;
        }
    }
    {   // wp1: 8192 f32
#pragma unroll
        for (int i = 0; i < 16; ++i) {
            int g = t + i * 128;
            float4 v = CF4(wp1 + g * 4);
            int p = g >> 4, c0 = (g & 15) * 4;
            F4(&wp1s[p * 65 + c0]) = v;
        }
    }
    tl[t] = (float)Ttr[(size_t)(LL - 1) * 128 + t];
    if (t < 64) xl[t] = (float)XT3[((size_t)b * LL + (LL - 1)) * HH + t];
    __syncthreads();
    if (t < 64) {
        const int o = t;
        float acc = bsk[3 * HH + o];
        for (int k = 0; k < 128; ++k) acc += ofs[o * 129 + k] * tl[k];
        for (int i = 0; i < 64; ++i) acc += wsks[o * 65 + i] * xl[i];
        x4[o] = acc;   // no gelu after last FNO layer
    }
    __syncthreads();
    {
        float acc = bp1[t];
        for (int h = 0; h < 64; ++h) acc += wp1s[t * 65 + h] * x4[h];
        y[t] = gelu_fast(acc);
    }
    __syncthreads();
    if (t < 8) {
        float acc = bp2[t];
        for (int p = 0; p < 128; ++p) acc += wp2[t * 128 + p] * y[p];
        out[b * 8 + t] = acc;   // float32 output
    }
}

// ---------------------------------------------------------------------------
extern "C" void kernel_launch(void* const* d_in, const int* in_sizes, int n_in,
                              void* d_out, int out_size, void* d_ws, size_t ws_size,
                              hipStream_t stream) {
    (void)in_sizes; (void)n_in; (void)out_size; (void)ws_size;
    const float* u   = (const float*)d_in[0];
    const float* z   = (const float*)d_in[1];
    // d_in[2] = t, unused by the reference
    const float* wl  = (const float*)d_in[3];
    const float* bl  = (const float*)d_in[4];
    const float* swr = (const float*)d_in[5];
    const float* swi = (const float*)d_in[6];
    const float* wsk = (const float*)d_in[7];
    const float* bsk = (const float*)d_in[8];
    const float* wp1 = (const float*)d_in[9];
    const float* bp1 = (const float*)d_in[10];
    const float* wp2 = (const float*)d_in[11];
    const float* bp2 = (const float*)d_in[12];
    float* out = (float*)d_out;

    f16* ws    = (f16*)d_ws;
    f16* XTa   = ws;                  // 8,388,608 h (16 MB)  [b][l][h]
    f16* XTb   = XTa + 8388608;       // 8,388,608 h
    f16* Tdt   = XTb + 8388608;       //   524,288 h  [m2][l]
    f16* Ttr   = Tdt + 524288;        //   524,288 h  [l][m2]
    f16* Ofh   = Ttr + 524288;        //   262,144 h  [b][o][m2]
    f16* wskh  = Ofh + 262144;        //    16,384 h
    f16* wrh   = wskh + 16384;        // 1,048,576 h
    f16* wih   = wrh + 1048576;       // 1,048,576 h
    // total ~40 MB. Y (4 MB f16 split-K partials) overlays the dead XT buffer.

    k_init<<<2560, 256, 0, stream>>>(u, z, wl, bl, wsk, swr, swi,
                                     Tdt, Ttr, wskh, wrh, wih, XTa);

    f16* xtc = XTa; f16* xtn = XTb;
    for (int layer = 0; layer < 4; ++layer) {
        f16* Y = xtn;   // dead until recon writes XTn (spec consumes Y first)
        k_dft<<<dim3(16, 32), 256, 0, stream>>>(xtc, Tdt, Y);
        k_spec<<<dim3(32, 16), 256, 0, stream>>>(Y, wrh, wih, Ofh, layer);
        if (layer < 3) {
            k_recon<<<dim3(32, 32), 256, 0, stream>>>(Ofh, xtc, Ttr, wskh, bsk,
                                                      xtn, layer);
            f16* tmp = xtc; xtc = xtn; xtn = tmp;
        } else {
            k_final<<<32, 128, 0, stream>>>(Ofh, xtc, Ttr, wsk, bsk,
                                            wp1, bp1, wp2, bp2, out);
        }
    }
}